// Round 7
// baseline (6204.499 us; speedup 1.0000x reference)
//
#include <hip/hip_runtime.h>
#include <math.h>

// Persistent-kernel NTM, R7: dedicated-master barrier with carried reductions.
// - Grid = 257 blocks: blocks 0..255 are workers (64 memory rows each, in LDS);
//   block 256 is a pure barrier-master that continuously polls arrival flags,
//   sums psA/psB when the phase needs a global scalar, and publishes
//   (epoch,value) packed in a single 64-bit atomic on 8 replicated go lines.
// - Workers never poll each other: arrival = 1 sc1 store; release = 1-lane
//   poll of one go line. No fences anywhere (mutable data all sc1 @ LLC,
//   read-only weights stay hot in per-XCD L2).
// - 6 barriers/step (L folded into J via deferred normalization carried by
//   the J->A barrier).
// - rvec partials: 32 atomic contention groups.

#define NBLK 256   // worker blocks
#define NTHR 256
#define Msz  16384
#define Dsz  256
#define Hsz  512
#define Isz  256
#define Tlen 128
#define RPB  64    // memory rows per worker block
#define NG   32    // rvec atomic groups
#define FSTR 32    // flag stride in u32 (128B line)
#define GSTR 16    // go stride in u64 (128B line)

struct Params {
  const float* in[34];
  float* out;
  float* ws;
};

__device__ __forceinline__ float wred64(float v){
#pragma unroll
  for (int o = 32; o > 0; o >>= 1) v += __shfl_xor(v, o, 64);
  return v;
}
__device__ __forceinline__ float wred32(float v){
#pragma unroll
  for (int o = 16; o > 0; o >>= 1) v += __shfl_xor(v, o, 32);
  return v;
}
__device__ __forceinline__ float sigm(float x){ return 1.f / (1.f + __expf(-x)); }
__device__ __forceinline__ float softplusf(float x){ return (x > 20.f) ? x : log1pf(__expf(x)); }

// agent-scope (LLC-coherent) accessors for mutable cross-block data
__device__ __forceinline__ void gstore(float* p, float v){
  __hip_atomic_store(p, v, __ATOMIC_RELAXED, __HIP_MEMORY_SCOPE_AGENT);
}
__device__ __forceinline__ float gload(const float* p){
  return __hip_atomic_load(p, __ATOMIC_RELAXED, __HIP_MEMORY_SCOPE_AGENT);
}
__device__ __forceinline__ void gstoreu(unsigned int* p, unsigned int v){
  __hip_atomic_store(p, v, __ATOMIC_RELAXED, __HIP_MEMORY_SCOPE_AGENT);
}
__device__ __forceinline__ unsigned int gloadu(const unsigned int* p){
  return __hip_atomic_load(p, __ATOMIC_RELAXED, __HIP_MEMORY_SCOPE_AGENT);
}
__device__ __forceinline__ void gstore64(unsigned long long* p, unsigned long long v){
  __hip_atomic_store(p, v, __ATOMIC_RELAXED, __HIP_MEMORY_SCOPE_AGENT);
}
__device__ __forceinline__ unsigned long long gload64(const unsigned long long* p){
  return __hip_atomic_load(p, __ATOMIC_RELAXED, __HIP_MEMORY_SCOPE_AGENT);
}

__global__ void __launch_bounds__(NTHR, 1)
ntm_kernel(Params P)
{
  const int b   = blockIdx.x;
  const int tid = threadIdx.x;
  const int wv  = tid >> 6;   // wave 0..3
  const int ln  = tid & 63;   // lane 0..63

  // ------- input pointers (setup_inputs dict order) -------
  const float* inputs  = P.in[0];
  const float* mem0    = P.in[1];
  const float* read_w0 = P.in[2];
  const float* write_w0= P.in[3];
  const float* W_ih = P.in[4];
  const float* W_hh = P.in[5];
  const float* b_ih = P.in[6];
  const float* b_hh = P.in[7];
  const float* Wo   = P.in[8];
  const float* bo   = P.in[9];
  const float* r_Wk = P.in[10]; const float* r_bk = P.in[11];
  const float* r_Wb = P.in[12]; const float* r_bb = P.in[13];
  const float* r_Wg = P.in[14]; const float* r_bg = P.in[15];
  const float* r_Ws = P.in[16]; const float* r_bs = P.in[17];
  const float* r_Wp = P.in[18]; const float* r_bp = P.in[19];
  const float* w_Wk = P.in[20]; const float* w_bk = P.in[21];
  const float* w_Wb = P.in[22]; const float* w_bb = P.in[23];
  const float* w_Wg = P.in[24]; const float* w_bg = P.in[25];
  const float* w_Ws = P.in[26]; const float* w_bs = P.in[27];
  const float* w_Wp = P.in[28]; const float* w_bp = P.in[29];
  const float* w_We = P.in[30]; const float* w_be = P.in[31];
  const float* w_Wa = P.in[32]; const float* w_ba = P.in[33];
  float* out = P.out;

  // ------- global scratch layout (floats) -------
  float* ws    = P.ws;
  float* harr  = ws;                 // 1024: h double buffer
  float* keyw  = ws + 1024;          // 256
  float* keyr  = keyw + 256;         // 256
  float* ersv  = keyr + 256;         // 256 (post-sigmoid erase)
  float* addv  = ersv + 256;         // 256
  float* scal  = addv + 256;         // 16 raw head scalars   (ends 2064)
  float* psA   = ws + 2064;          // 256 per-block partial e-sums
  float* psB   = ws + 2320;          // 256 per-block partial sharpened-w sums
  float* eF    = ws + 2576;          // 256 e[first row] per block
  float* eL    = ws + 2832;
  float* pF    = ws + 3088;
  float* pL    = ws + 3344;          // ends 3600
  float* parts = ws + 3616;          // NG*256 = 8192 floats (ends 11808)
  unsigned int*       flags = (unsigned int*)(ws + 11808);       // 256*FSTR u32 (ends 20000)
  unsigned long long* go64  = (unsigned long long*)(ws + 20000); // 8*GSTR u64 (ends 20256), 128B-aligned
  unsigned int*       flg   = (unsigned int*)(ws + 20256);       // sentinel, own line

  // =================== MASTER BLOCK (pure barrier service) ===================
  if (b == NBLK){
    if (tid >= 64) return;            // single wave
    // zero sync vars, then open the gate
#pragma unroll
    for (int k = 0; k < 4; ++k) gstoreu(&flags[(k * 64 + ln) * FSTR], 0u);
    if (ln < 8) gstore64(&go64[ln * GSTR], 0ull);
    __builtin_amdgcn_s_waitcnt(0);
    if (ln == 0) gstoreu(flg, 0xC0FFEEu);

    unsigned int e = 1;
    const int total = 1 + Tlen * 6;   // INIT2 + 6/step
    for (int k = 0; k < total; ++k){
      for (;;){
        unsigned int a0 = gloadu(&flags[ln * FSTR]);
        unsigned int a1 = gloadu(&flags[(64 + ln) * FSTR]);
        unsigned int a2 = gloadu(&flags[(128 + ln) * FSTR]);
        unsigned int a3 = gloadu(&flags[(192 + ln) * FSTR]);
        bool ok = ((int)(a0 - e) >= 0) && ((int)(a1 - e) >= 0)
               && ((int)(a2 - e) >= 0) && ((int)(a3 - e) >= 0);
        if (__all(ok)) break;
        __builtin_amdgcn_s_sleep(1);
      }
      int ph = (k == 0) ? -1 : (k - 1) % 6;   // A C D F H J = 0..5
      float v = 0.f;
      if (ph == 2 || ph == 4){        // D, H carry sum(psA)
        v = gload(&psA[ln]) + gload(&psA[64 + ln]) + gload(&psA[128 + ln]) + gload(&psA[192 + ln]);
        v = wred64(v);
      } else if (ph == 3 || ph == 5){ // F, J carry sum(psB)
        v = gload(&psB[ln]) + gload(&psB[64 + ln]) + gload(&psB[128 + ln]) + gload(&psB[192 + ln]);
        v = wred64(v);
      }
      unsigned long long pk = ((unsigned long long)e << 32) | (unsigned long long)__float_as_uint(v);
      if (ln < 8) gstore64(&go64[ln * GSTR], pk);
      ++e;
    }
    return;
  }

  // =================== WORKER BLOCKS ===================
  __shared__ float s_mem[RPB * Dsz];   // 64KB: this block's memory rows
  __shared__ float s_co[Hsz];
  __shared__ float s_a[256], s_b[256], s_c[256];
  __shared__ float s_rv[256];          // current (normalized) read vector
  __shared__ float s_norm[RPB];
  __shared__ float s_e[RPB];
  __shared__ float s_bw[RPB];          // sharpened (unnormalized) weights
  __shared__ float s_rw[RPB];          // normalized read weights
  __shared__ float s_ww[RPB];          // normalized write weights
  __shared__ float s_red[4];
  __shared__ float s_lg[8];
  __shared__ float s_wsum[4];
  __shared__ float s_cst[2];
  __shared__ float s_gval;

  unsigned int ep = 1;

  // ------- INIT1 (ws poisoned 0xAA each launch; wait for master's gate) -------
  {
    if (b == 0){
#pragma unroll
      for (int k = 0; k < 4; ++k) gstore(&harr[k * 256 + tid], 0.f);
    }
    if (b < NG) gstore(&parts[b * 256 + tid], 0.f);
    if (tid < RPB){
      s_rw[tid] = read_w0[b * RPB + tid];
      s_ww[tid] = write_w0[b * RPB + tid];
    }
    if (tid < 2) s_cst[tid] = 0.f;
    __syncthreads();
    if (tid == 0){
      while (gloadu(flg) != 0xC0FFEEu) __builtin_amdgcn_s_sleep(2);
    }
    __syncthreads();
  }

  // barrier: arrival store + 1-lane poll of packed (epoch,value) go line
  auto gbar = [&]()->float{
    __syncthreads();                   // drains all waves' sc1 stores (vmcnt 0)
    if (tid == 0){
      gstoreu(&flags[b * FSTR], ep);
      unsigned long long pk;
      do { pk = gload64(&go64[(b & 7) * GSTR]); }
      while ((int)((unsigned int)(pk >> 32) - ep) < 0);
      s_gval = __uint_as_float((unsigned int)(pk & 0xffffffffu));
    }
    __syncthreads();
    ++ep;
    return s_gval;
  };

  auto bred256 = [&](float v)->float{
    v = wred64(v);
    __syncthreads();
    if (ln == 0) s_red[wv] = v;
    __syncthreads();
    return s_red[0] + s_red[1] + s_red[2] + s_red[3];
  };

  // shift + sharpen (S = global content-softmax denominator, barrier-carried)
  auto shiftSharpen = [&](int si, float* s_prevw, float S){
    float g     = sigm(gload(&scal[si + 1]));
    float gamma = softplusf(gload(&scal[si + 2])) + 1.f;
    float a0 = gload(&scal[si + 3]), a1 = gload(&scal[si + 4]), a2 = gload(&scal[si + 5]);
    float mx = fmaxf(a0, fmaxf(a1, a2));
    float e0 = __expf(a0 - mx), e1 = __expf(a1 - mx), e2 = __expf(a2 - mx);
    float idn = 1.f / (e0 + e1 + e2);
    float s0 = e0 * idn, s1 = e1 * idn, s2 = e2 * idn;
    float invS = 1.f / S;
    float w = 0.f;
    if (tid < RPB){
      float gc = g * invS, gp = 1.f - g;
      float em = s_e[tid],  pm = s_prevw[tid];
      float e1n = (tid < RPB-1) ? s_e[tid+1]     : gload(&eF[(b + 1) & (NBLK-1)]);
      float p1n = (tid < RPB-1) ? s_prevw[tid+1] : gload(&pF[(b + 1) & (NBLK-1)]);
      float e2n = (tid > 0)     ? s_e[tid-1]     : gload(&eL[(b - 1) & (NBLK-1)]);
      float p2n = (tid > 0)     ? s_prevw[tid-1] : gload(&pL[(b - 1) & (NBLK-1)]);
      float gwm = gc * em  + gp * pm;
      float gw1 = gc * e1n + gp * p1n;   // roll(gw,-1)
      float gw2 = gc * e2n + gp * p2n;   // roll(gw,+1)
      float sh = s0 * gw1 + s1 * gwm + s2 * gw2;
      w = powf(sh, gamma);
      s_bw[tid] = w;
    }
    float tot = wred64(w);
    if (tid == 0) gstore(&psB[b], tot);
  };

  // ------- INIT2: memory rows -> LDS, norms, initial read_vec partials -------
  {
#pragma unroll 1
    for (int it = 0; it < 16; ++it){
      int ml = it * 4 + wv;
      int m  = b * RPB + ml;
      float4 v = *(const float4*)(mem0 + (size_t)m * Dsz + ln * 4);
      *(float4*)(&s_mem[ml * Dsz + ln * 4]) = v;
      float n2 = v.x*v.x + v.y*v.y + v.z*v.z + v.w*v.w;
      n2 = wred64(n2);
      if (ln == 0) s_norm[ml] = sqrtf(n2);
    }
    __syncthreads();
    float acc = 0.f;
#pragma unroll 1
    for (int j = 0; j < RPB; ++j) acc += s_rw[j] * s_mem[j * Dsz + tid];
    atomicAdd(&parts[(b & (NG-1)) * 256 + tid], acc);
  }
  gbar();   // INIT2 barrier (no value)

  float Srcarry = 1.f;   // J->A carried read-weight normalizer

  // =================== time loop ===================
  for (int t = 0; t < Tlen; ++t){
    const float* hprev = harr + (t & 1) * Hsz;
    float*       hcur  = harr + ((t + 1) & 1) * Hsz;
    const float* xt    = inputs + (size_t)t * Isz;

    // ---- A: normalize rw + rvec (deferred by Sr); LSTM gates + elementwise ----
    {
      float SrDiv = (t == 0) ? 1.f : (Srcarry + 1e-8f);
      if (t > 0 && tid < RPB) s_rw[tid] = s_bw[tid] / SrDiv;
      s_co[tid] = gload(&hprev[tid]); s_co[256 + tid] = gload(&hprev[256 + tid]);
      s_a[tid] = xt[tid];
      float rvv = 0.f;
#pragma unroll
      for (int p = 0; p < NG; ++p) rvv += gload(&parts[p * 256 + tid]);
      s_rv[tid] = rvv / SrDiv;
      __syncthreads();
      int dd = tid >> 5;          // 0..7 : (gate 0..3) x (hidden offset 0..1)
      int l  = tid & 31;
      int jj = (b << 1) + (dd & 1);
      int g  = dd >> 1;
      int r  = g * Hsz + jj;
      const float* wi = W_ih + (size_t)r * (Isz + Dsz);
      const float* wh = W_hh + (size_t)r * Hsz;
      float acc = 0.f;
#pragma unroll
      for (int it = 0; it < 4; ++it){
        int k = it * 128 + l * 4;
        float4 a  = *(const float4*)(wi + k);
        float4 x  = (k < Isz) ? *(const float4*)(&s_a[k]) : *(const float4*)(&s_rv[k - Isz]);
        acc += a.x*x.x + a.y*x.y + a.z*x.z + a.w*x.w;
        float4 hw = *(const float4*)(wh + k);
        float4 hv = *(const float4*)(&s_co[k]);
        acc += hw.x*hv.x + hw.y*hv.y + hw.z*hv.z + hw.w*hv.w;
      }
      acc = wred32(acc);
      if (l == 0) s_lg[dd] = acc + b_ih[r] + b_hh[r];
      __syncthreads();
      if (tid < 2){
        int j = (b << 1) + tid;
        float iv = s_lg[0 + tid], fv = s_lg[2 + tid], gv = s_lg[4 + tid], ov = s_lg[6 + tid];
        float cn = sigm(fv) * s_cst[tid] + sigm(iv) * tanhf(gv);
        s_cst[tid] = cn;
        gstore(&hcur[j], sigm(ov) * tanhf(cn));
      }
    }
    gbar();

    // ---- C: head projections + output GEMV (8 slots/block); zero rvec parts ----
    {
      s_co[tid] = gload(&hcur[tid]); s_co[256 + tid] = gload(&hcur[256 + tid]);
      if (b < NG) gstore(&parts[b * 256 + tid], 0.f);
      __syncthreads();
#pragma unroll
      for (int q = 0; q < 2; ++q){
        int slot = b * 8 + wv * 2 + q;
        if (slot < 1292){
          const float* Wrow = nullptr; float bias = 0.f; int len = 512;
          float* dst = nullptr; bool act = false; bool plain = false;
          if (slot < 256){ Wrow = w_Wk + (size_t)slot * Hsz; bias = w_bk[slot]; dst = keyw + slot; }
          else if (slot < 512){ int i = slot - 256; Wrow = w_We + (size_t)i * Hsz; bias = w_be[i]; dst = ersv + i; act = true; }
          else if (slot < 768){ int i = slot - 512; Wrow = w_Wa + (size_t)i * Hsz; bias = w_ba[i]; dst = addv + i; }
          else if (slot < 1024){ int i = slot - 768; Wrow = r_Wk + (size_t)i * Hsz; bias = r_bk[i]; dst = keyr + i; }
          else if (slot < 1280){ int i = slot - 1024; Wrow = Wo + (size_t)i * (Hsz + Dsz); bias = bo[i]; len = 768; dst = out + (size_t)t * Isz + i; plain = true; }
          else {
            int i = slot - 1280;
            int ii = (i >= 6) ? i - 6 : i;
            bool rh = (i >= 6);
            const float *Wt, *bt; int row = 0;
            if (ii == 0){ Wt = rh ? r_Wb : w_Wb; bt = rh ? r_bb : w_bb; }
            else if (ii == 1){ Wt = rh ? r_Wg : w_Wg; bt = rh ? r_bg : w_bg; }
            else if (ii == 2){ Wt = rh ? r_Wp : w_Wp; bt = rh ? r_bp : w_bp; }
            else { Wt = rh ? r_Ws : w_Ws; bt = rh ? r_bs : w_bs; row = ii - 3; }
            Wrow = Wt + (size_t)row * Hsz; bias = bt[row]; dst = scal + i;
          }
          float acc = 0.f;
          if (len == 512){
            int k = ln * 8;
            float4 a0 = *(const float4*)(Wrow + k);
            float4 a1 = *(const float4*)(Wrow + k + 4);
            float4 c0 = *(const float4*)(&s_co[k]);
            float4 c1 = *(const float4*)(&s_co[k + 4]);
            acc = a0.x*c0.x + a0.y*c0.y + a0.z*c0.z + a0.w*c0.w
                + a1.x*c1.x + a1.y*c1.y + a1.z*c1.z + a1.w*c1.w;
          } else {
#pragma unroll 1
            for (int kk = ln; kk < 768; kk += 64){
              float x = (kk < Hsz) ? s_co[kk] : s_rv[kk - Hsz];
              acc += Wrow[kk] * x;
            }
          }
          acc = wred64(acc);
          if (ln == 0){
            float v = acc + bias;
            if (act) v = sigm(v);
            if (plain) *dst = v; else gstore(dst, v);
          }
        }
      }
    }
    gbar();

    // ---- D: write-head content scores; publish psA + boundaries ----
    {
      s_a[tid] = gload(&keyw[tid]);
      float nk2 = bred256(s_a[tid] * s_a[tid]);
      float beta  = softplusf(gload(&scal[0]));
      float invbk = beta / fmaxf(sqrtf(nk2), 1e-12f);
      float esum = 0.f;
#pragma unroll 1
      for (int it = 0; it < 16; ++it){
        int ml = it * 4 + wv;
        float4 v  = *(const float4*)(&s_mem[ml * Dsz + ln * 4]);
        float4 kv = *(const float4*)(&s_a[ln * 4]);
        float d = v.x*kv.x + v.y*kv.y + v.z*kv.z + v.w*kv.w;
        d = wred64(d);
        float score = d * invbk / fmaxf(s_norm[ml], 1e-12f);
        float e = __expf(score - beta);
        if (ln == 0){ s_e[ml] = e; esum += e; }
      }
      if (ln == 0) s_wsum[wv] = esum;
      __syncthreads();
      if (tid == 0){
        gstore(&psA[b], s_wsum[0] + s_wsum[1] + s_wsum[2] + s_wsum[3]);
        gstore(&eF[b], s_e[0]);  gstore(&eL[b], s_e[RPB-1]);
        gstore(&pF[b], s_ww[0]); gstore(&pL[b], s_ww[RPB-1]);
      }
    }
    float S_w = gbar();   // carried: sum(psA) = write-head softmax denom

    // ---- F: write-head interpolate + shift + sharpen ----
    shiftSharpen(0, s_ww, S_w);
    float Sw = gbar();    // carried: sum(psB) = write-weight normalizer

    // ---- H: normalize ww, memory erase/add update, new norms + read scores ----
    {
      s_a[tid] = gload(&ersv[tid]); s_b[tid] = gload(&addv[tid]); s_c[tid] = gload(&keyr[tid]);
      float nk2 = bred256(s_c[tid] * s_c[tid]);
      float beta  = softplusf(gload(&scal[6]));
      float invbk = beta / fmaxf(sqrtf(nk2), 1e-12f);
      float invSw = 1.f / (Sw + 1e-8f);
      if (tid < RPB) s_ww[tid] = s_bw[tid] * invSw;
      float esum = 0.f;
#pragma unroll 1
      for (int it = 0; it < 16; ++it){
        int ml = it * 4 + wv;
        float wwm = s_bw[ml] * invSw;
        int off = ml * Dsz + ln * 4;
        float4 mv = *(const float4*)(&s_mem[off]);
        float4 er = *(const float4*)(&s_a[ln * 4]);
        float4 ad = *(const float4*)(&s_b[ln * 4]);
        float4 kr = *(const float4*)(&s_c[ln * 4]);
        float4 nv;
        nv.x = mv.x * (1.f - wwm * er.x) + wwm * ad.x;
        nv.y = mv.y * (1.f - wwm * er.y) + wwm * ad.y;
        nv.z = mv.z * (1.f - wwm * er.z) + wwm * ad.z;
        nv.w = mv.w * (1.f - wwm * er.w) + wwm * ad.w;
        *(float4*)(&s_mem[off]) = nv;
        float n2 = nv.x*nv.x + nv.y*nv.y + nv.z*nv.z + nv.w*nv.w;
        float dt = nv.x*kr.x + nv.y*kr.y + nv.z*kr.z + nv.w*kr.w;
        n2 = wred64(n2);
        dt = wred64(dt);
        float nr = sqrtf(n2);
        if (ln == 0) s_norm[ml] = nr;
        float score = dt * invbk / fmaxf(nr, 1e-12f);
        float e = __expf(score - beta);
        if (ln == 0){ s_e[ml] = e; esum += e; }
      }
      if (ln == 0) s_wsum[wv] = esum;
      __syncthreads();
      if (tid == 0){
        gstore(&psA[b], s_wsum[0] + s_wsum[1] + s_wsum[2] + s_wsum[3]);
        gstore(&eF[b], s_e[0]);  gstore(&eL[b], s_e[RPB-1]);
        gstore(&pF[b], s_rw[0]); gstore(&pL[b], s_rw[RPB-1]);
      }
    }
    float S_r = gbar();   // carried: read-head softmax denom

    // ---- J: read-head shift+sharpen; UNNORMALIZED rvec partials (L folded in) ----
    {
      shiftSharpen(6, s_rw, S_r);
      __syncthreads();
      float acc = 0.f;
#pragma unroll 1
      for (int j = 0; j < RPB; ++j) acc += s_bw[j] * s_mem[j * Dsz + tid];
      atomicAdd(&parts[(b & (NG-1)) * 256 + tid], acc);
    }
    Srcarry = gbar();     // carried: sum(psB) = read-weight normalizer for A(t+1)
  }
}

extern "C" void kernel_launch(void* const* d_in, const int* in_sizes, int n_in,
                              void* d_out, int out_size, void* d_ws, size_t ws_size,
                              hipStream_t stream)
{
  (void)in_sizes; (void)out_size;
  if (n_in < 34) return;
  if (ws_size < (size_t)131072) return;   // ~82KB scratch needed; require 128KB
  Params P;
  for (int i = 0; i < 34; ++i) P.in[i] = (const float*)d_in[i];
  P.out = (float*)d_out;
  P.ws  = (float*)d_ws;
  hipLaunchKernelGGL(ntm_kernel, dim3(NBLK + 1), dim3(NTHR), 0, stream, P);
}

// Round 8
// 5531.112 us; speedup vs baseline: 1.1217x; 1.1217x over previous
//
#include <hip/hip_runtime.h>
#include <math.h>

// Persistent-kernel NTM, R8: 128 worker blocks x 512 threads (128 rows each,
// 128KB LDS) + 1 dedicated master block = 129 blocks <= 256 CUs (no CU
// co-location). Master polls 128 arrival flags, carries psA/psB reductions in
// a packed (epoch,value) 64-bit go word on 8 replicated lines. No fences:
// mutable cross-block data all sc1 (LLC-coherent); weights stay hot in L2.
// 6 barriers/step.

#define NBLK 128   // worker blocks
#define NTHR 512
#define Msz  16384
#define Dsz  256
#define Hsz  512
#define Isz  256
#define Tlen 128
#define RPB  128   // memory rows per worker block
#define NG   16    // rvec atomic groups
#define FSTR 32    // flag stride in u32 (128B line)
#define GSTR 16    // go stride in u64 (128B line)

struct Params {
  const float* in[34];
  float* out;
  float* ws;
};

__device__ __forceinline__ float wred64(float v){
#pragma unroll
  for (int o = 32; o > 0; o >>= 1) v += __shfl_xor(v, o, 64);
  return v;
}
__device__ __forceinline__ float wred32(float v){
#pragma unroll
  for (int o = 16; o > 0; o >>= 1) v += __shfl_xor(v, o, 32);
  return v;
}
__device__ __forceinline__ float sigm(float x){ return 1.f / (1.f + __expf(-x)); }
__device__ __forceinline__ float softplusf(float x){ return (x > 20.f) ? x : log1pf(__expf(x)); }

__device__ __forceinline__ void gstore(float* p, float v){
  __hip_atomic_store(p, v, __ATOMIC_RELAXED, __HIP_MEMORY_SCOPE_AGENT);
}
__device__ __forceinline__ float gload(const float* p){
  return __hip_atomic_load(p, __ATOMIC_RELAXED, __HIP_MEMORY_SCOPE_AGENT);
}
__device__ __forceinline__ void gstoreu(unsigned int* p, unsigned int v){
  __hip_atomic_store(p, v, __ATOMIC_RELAXED, __HIP_MEMORY_SCOPE_AGENT);
}
__device__ __forceinline__ unsigned int gloadu(const unsigned int* p){
  return __hip_atomic_load(p, __ATOMIC_RELAXED, __HIP_MEMORY_SCOPE_AGENT);
}
__device__ __forceinline__ void gstore64(unsigned long long* p, unsigned long long v){
  __hip_atomic_store(p, v, __ATOMIC_RELAXED, __HIP_MEMORY_SCOPE_AGENT);
}
__device__ __forceinline__ unsigned long long gload64(const unsigned long long* p){
  return __hip_atomic_load(p, __ATOMIC_RELAXED, __HIP_MEMORY_SCOPE_AGENT);
}

__global__ void __launch_bounds__(NTHR, 1)
ntm_kernel(Params P)
{
  const int b   = blockIdx.x;
  const int tid = threadIdx.x;
  const int wv  = tid >> 6;   // wave 0..7
  const int ln  = tid & 63;

  // ------- inputs (setup_inputs dict order) -------
  const float* inputs  = P.in[0];
  const float* mem0    = P.in[1];
  const float* read_w0 = P.in[2];
  const float* write_w0= P.in[3];
  const float* W_ih = P.in[4];
  const float* W_hh = P.in[5];
  const float* b_ih = P.in[6];
  const float* b_hh = P.in[7];
  const float* Wo   = P.in[8];
  const float* bo   = P.in[9];
  const float* r_Wk = P.in[10]; const float* r_bk = P.in[11];
  const float* r_Wb = P.in[12]; const float* r_bb = P.in[13];
  const float* r_Wg = P.in[14]; const float* r_bg = P.in[15];
  const float* r_Ws = P.in[16]; const float* r_bs = P.in[17];
  const float* r_Wp = P.in[18]; const float* r_bp = P.in[19];
  const float* w_Wk = P.in[20]; const float* w_bk = P.in[21];
  const float* w_Wb = P.in[22]; const float* w_bb = P.in[23];
  const float* w_Wg = P.in[24]; const float* w_bg = P.in[25];
  const float* w_Ws = P.in[26]; const float* w_bs = P.in[27];
  const float* w_Wp = P.in[28]; const float* w_bp = P.in[29];
  const float* w_We = P.in[30]; const float* w_be = P.in[31];
  const float* w_Wa = P.in[32]; const float* w_ba = P.in[33];
  float* out = P.out;

  // ------- global scratch (floats) -------
  float* ws    = P.ws;
  float* harr  = ws;                  // 1024
  float* keyw  = ws + 1024;           // 256
  float* keyr  = ws + 1280;           // 256
  float* ersv  = ws + 1536;           // 256
  float* addv  = ws + 1792;           // 256
  float* scal  = ws + 2048;           // 16
  float* psA   = ws + 2064;           // 128
  float* psB   = ws + 2192;           // 128
  float* eF    = ws + 2320;           // 128
  float* eL    = ws + 2448;           // 128
  float* pF    = ws + 2576;           // 128
  float* pL    = ws + 2704;           // 128 (ends 2832)
  float* parts = ws + 2848;           // NG*256 = 4096 (ends 6944; 128B aligned)
  unsigned int*       flags = (unsigned int*)(ws + 6944);   // 128*FSTR u32 (ends f+4096)
  unsigned long long* go64  = (unsigned long long*)(ws + 11040); // 8*GSTR u64 (128B aligned)
  unsigned int*       flg   = (unsigned int*)(ws + 11296);  // sentinel

  // =================== MASTER BLOCK ===================
  if (b == NBLK){
    if (tid >= 64) return;            // single wave, own CU
#pragma unroll
    for (int k = 0; k < 2; ++k) gstoreu(&flags[(k * 64 + ln) * FSTR], 0u);
    if (ln < 8) gstore64(&go64[ln * GSTR], 0ull);
    __builtin_amdgcn_s_waitcnt(0);
    if (ln == 0) gstoreu(flg, 0xC0FFEEu);

    unsigned int e = 1;
    const int total = 1 + Tlen * 6;
    for (int k = 0; k < total; ++k){
      for (;;){
        unsigned int a0 = gloadu(&flags[ln * FSTR]);
        unsigned int a1 = gloadu(&flags[(64 + ln) * FSTR]);
        bool ok = ((int)(a0 - e) >= 0) && ((int)(a1 - e) >= 0);
        if (__all(ok)) break;
        __builtin_amdgcn_s_sleep(1);
      }
      int ph = (k == 0) ? -1 : (k - 1) % 6;   // A C D F H J = 0..5
      float v = 0.f;
      if (ph == 2 || ph == 4){        // D, H carry sum(psA)
        v = wred64(gload(&psA[ln]) + gload(&psA[64 + ln]));
      } else if (ph == 3 || ph == 5){ // F, J carry sum(psB)
        v = wred64(gload(&psB[ln]) + gload(&psB[64 + ln]));
      }
      unsigned long long pk = ((unsigned long long)e << 32) | (unsigned long long)__float_as_uint(v);
      if (ln < 8) gstore64(&go64[ln * GSTR], pk);
      ++e;
    }
    return;
  }

  // =================== WORKER BLOCKS ===================
  __shared__ float s_mem[RPB * Dsz];   // 128KB
  __shared__ float s_co[Hsz];          // 512
  __shared__ float s_a[256], s_b[256], s_c[256];
  __shared__ float s_rv[256];
  __shared__ float s_norm[RPB];
  __shared__ float s_e[RPB];
  __shared__ float s_bw[RPB];
  __shared__ float s_rw[RPB];
  __shared__ float s_ww[RPB];
  __shared__ float s_red[8];
  __shared__ float s_lg[16];
  __shared__ float s_wsum[8];
  __shared__ float s_w2[2];
  __shared__ float s_cst[4];
  __shared__ float s_gval;

  unsigned int ep = 1;

  // ------- INIT1 -------
  {
    if (b == 0){
#pragma unroll
      for (int k = 0; k < 2; ++k) gstore(&harr[k * 512 + tid], 0.f);
    }
    if (b < NG && tid < 256) gstore(&parts[b * 256 + tid], 0.f);
    if (tid < RPB){
      s_rw[tid] = read_w0[b * RPB + tid];
      s_ww[tid] = write_w0[b * RPB + tid];
    }
    if (tid < 4) s_cst[tid] = 0.f;
    __syncthreads();
    if (tid == 0){
      while (gloadu(flg) != 0xC0FFEEu) __builtin_amdgcn_s_sleep(2);
    }
    __syncthreads();
  }

  auto gbar = [&]()->float{
    __syncthreads();                   // vmcnt(0): all sc1 stores drained
    if (tid == 0){
      gstoreu(&flags[b * FSTR], ep);
      unsigned long long pk;
      do { pk = gload64(&go64[(b & 7) * GSTR]); }
      while ((int)((unsigned int)(pk >> 32) - ep) < 0);
      s_gval = __uint_as_float((unsigned int)(pk & 0xffffffffu));
    }
    __syncthreads();
    ++ep;
    return s_gval;
  };

  auto bred512 = [&](float v)->float{
    v = wred64(v);
    __syncthreads();
    if (ln == 0) s_red[wv] = v;
    __syncthreads();
    return s_red[0] + s_red[1] + s_red[2] + s_red[3]
         + s_red[4] + s_red[5] + s_red[6] + s_red[7];
  };

  auto shiftSharpen = [&](int si, float* s_prevw, float S){
    float g     = sigm(gload(&scal[si + 1]));
    float gamma = softplusf(gload(&scal[si + 2])) + 1.f;
    float a0 = gload(&scal[si + 3]), a1 = gload(&scal[si + 4]), a2 = gload(&scal[si + 5]);
    float mx = fmaxf(a0, fmaxf(a1, a2));
    float e0 = __expf(a0 - mx), e1 = __expf(a1 - mx), e2 = __expf(a2 - mx);
    float idn = 1.f / (e0 + e1 + e2);
    float s0 = e0 * idn, s1 = e1 * idn, s2 = e2 * idn;
    float invS = 1.f / S;
    float w = 0.f;
    if (tid < RPB){
      float gc = g * invS, gp = 1.f - g;
      float em = s_e[tid],  pm = s_prevw[tid];
      float e1n = (tid < RPB-1) ? s_e[tid+1]     : gload(&eF[(b + 1) & (NBLK-1)]);
      float p1n = (tid < RPB-1) ? s_prevw[tid+1] : gload(&pF[(b + 1) & (NBLK-1)]);
      float e2n = (tid > 0)     ? s_e[tid-1]     : gload(&eL[(b - 1) & (NBLK-1)]);
      float p2n = (tid > 0)     ? s_prevw[tid-1] : gload(&pL[(b - 1) & (NBLK-1)]);
      float gwm = gc * em  + gp * pm;
      float gw1 = gc * e1n + gp * p1n;   // roll(gw,-1)
      float gw2 = gc * e2n + gp * p2n;   // roll(gw,+1)
      float sh = s0 * gw1 + s1 * gwm + s2 * gw2;
      w = powf(sh, gamma);
      s_bw[tid] = w;
    }
    float tot = wred64(w);               // waves 0,1 hold partials
    if (ln == 0 && wv < 2) s_w2[wv] = tot;
    __syncthreads();
    if (tid == 0) gstore(&psB[b], s_w2[0] + s_w2[1]);
  };

  // ------- INIT2: memory rows -> LDS, norms, initial rvec partials -------
  {
#pragma unroll 1
    for (int it = 0; it < 16; ++it){
      int ml = it * 8 + wv;
      int m  = b * RPB + ml;
      float4 v = *(const float4*)(mem0 + (size_t)m * Dsz + ln * 4);
      *(float4*)(&s_mem[ml * Dsz + ln * 4]) = v;
      float n2 = wred64(v.x*v.x + v.y*v.y + v.z*v.z + v.w*v.w);
      if (ln == 0) s_norm[ml] = sqrtf(n2);
    }
    __syncthreads();
    int col = tid & 255, half = tid >> 8;
    float acc = 0.f;
#pragma unroll 1
    for (int j = half * 64; j < half * 64 + 64; ++j) acc += s_rw[j] * s_mem[j * Dsz + col];
    if (half == 0) s_a[col] = acc;
    __syncthreads();
    if (half == 1) atomicAdd(&parts[(b & (NG-1)) * 256 + col], acc + s_a[col]);
  }
  gbar();

  float Srcarry = 1.f;

  // =================== time loop ===================
  for (int t = 0; t < Tlen; ++t){
    const float* hprev = harr + (t & 1) * Hsz;
    float*       hcur  = harr + ((t + 1) & 1) * Hsz;
    const float* xt    = inputs + (size_t)t * Isz;

    // ---- A: deferred rw/rvec normalize; LSTM gates (block owns units 4b..4b+3) ----
    {
      float SrDiv = (t == 0) ? 1.f : (Srcarry + 1e-8f);
      if (t > 0 && tid < RPB) s_rw[tid] = s_bw[tid] / SrDiv;
      s_co[tid] = gload(&hprev[tid]);
      if (tid < 256){
        s_a[tid] = xt[tid];
        float rvv = 0.f;
#pragma unroll
        for (int p = 0; p < NG; ++p) rvv += gload(&parts[p * 256 + tid]);
        s_rv[tid] = rvv / SrDiv;
      }
      __syncthreads();
      int dd = tid >> 5;          // 0..15: gate = dd>>2, unit = dd&3
      int l  = tid & 31;
      int jj = (b << 2) + (dd & 3);
      int g  = dd >> 2;
      int r  = g * Hsz + jj;
      const float* wi = W_ih + (size_t)r * (Isz + Dsz);
      const float* wh = W_hh + (size_t)r * Hsz;
      float acc = 0.f;
#pragma unroll
      for (int it = 0; it < 4; ++it){
        int k = it * 128 + l * 4;
        float4 a  = *(const float4*)(wi + k);
        float4 x  = (k < Isz) ? *(const float4*)(&s_a[k]) : *(const float4*)(&s_rv[k - Isz]);
        acc += a.x*x.x + a.y*x.y + a.z*x.z + a.w*x.w;
        float4 hw = *(const float4*)(wh + k);
        float4 hv = *(const float4*)(&s_co[k]);
        acc += hw.x*hv.x + hw.y*hv.y + hw.z*hv.z + hw.w*hv.w;
      }
      acc = wred32(acc);
      if (l == 0) s_lg[dd] = acc + b_ih[r] + b_hh[r];
      __syncthreads();
      if (tid < 4){
        int j = (b << 2) + tid;
        float iv = s_lg[tid], fv = s_lg[4 + tid], gv = s_lg[8 + tid], ov = s_lg[12 + tid];
        float cn = sigm(fv) * s_cst[tid] + sigm(iv) * tanhf(gv);
        s_cst[tid] = cn;
        gstore(&hcur[j], sigm(ov) * tanhf(cn));
      }
    }
    gbar();

    // ---- C: head projections + output GEMV (11 slots/block); zero rvec parts ----
    {
      s_co[tid] = gload(&hcur[tid]);
      if (b < NG && tid < 256) gstore(&parts[b * 256 + tid], 0.f);
      __syncthreads();
#pragma unroll
      for (int qi = 0; qi < 2; ++qi){
        int idx = qi * 8 + wv;        // 0..15
        int slot = b * 11 + idx;
        if (idx < 11 && slot < 1292){
          const float* Wrow = nullptr; float bias = 0.f; int len = 512;
          float* dst = nullptr; bool act = false; bool plain = false;
          if (slot < 256){ Wrow = w_Wk + (size_t)slot * Hsz; bias = w_bk[slot]; dst = keyw + slot; }
          else if (slot < 512){ int i = slot - 256; Wrow = w_We + (size_t)i * Hsz; bias = w_be[i]; dst = ersv + i; act = true; }
          else if (slot < 768){ int i = slot - 512; Wrow = w_Wa + (size_t)i * Hsz; bias = w_ba[i]; dst = addv + i; }
          else if (slot < 1024){ int i = slot - 768; Wrow = r_Wk + (size_t)i * Hsz; bias = r_bk[i]; dst = keyr + i; }
          else if (slot < 1280){ int i = slot - 1024; Wrow = Wo + (size_t)i * (Hsz + Dsz); bias = bo[i]; len = 768; dst = out + (size_t)t * Isz + i; plain = true; }
          else {
            int i = slot - 1280;
            int ii = (i >= 6) ? i - 6 : i;
            bool rh = (i >= 6);
            const float *Wt, *bt; int row = 0;
            if (ii == 0){ Wt = rh ? r_Wb : w_Wb; bt = rh ? r_bb : w_bb; }
            else if (ii == 1){ Wt = rh ? r_Wg : w_Wg; bt = rh ? r_bg : w_bg; }
            else if (ii == 2){ Wt = rh ? r_Wp : w_Wp; bt = rh ? r_bp : w_bp; }
            else { Wt = rh ? r_Ws : w_Ws; bt = rh ? r_bs : w_bs; row = ii - 3; }
            Wrow = Wt + (size_t)row * Hsz; bias = bt[row]; dst = scal + i;
          }
          float acc = 0.f;
          if (len == 512){
            int k = ln * 8;
            float4 a0 = *(const float4*)(Wrow + k);
            float4 a1 = *(const float4*)(Wrow + k + 4);
            float4 c0 = *(const float4*)(&s_co[k]);
            float4 c1 = *(const float4*)(&s_co[k + 4]);
            acc = a0.x*c0.x + a0.y*c0.y + a0.z*c0.z + a0.w*c0.w
                + a1.x*c1.x + a1.y*c1.y + a1.z*c1.z + a1.w*c1.w;
          } else {
#pragma unroll 1
            for (int kk = ln; kk < 768; kk += 64){
              float x = (kk < Hsz) ? s_co[kk] : s_rv[kk - Hsz];
              acc += Wrow[kk] * x;
            }
          }
          acc = wred64(acc);
          if (ln == 0){
            float v = acc + bias;
            if (act) v = sigm(v);
            if (plain) *dst = v; else gstore(dst, v);
          }
        }
      }
    }
    gbar();

    // ---- D: write-head content scores; publish psA + boundaries ----
    {
      if (tid < 256) s_a[tid] = gload(&keyw[tid]);
      float nk2 = bred512((tid < 256) ? s_a[tid] * s_a[tid] : 0.f);
      float beta  = softplusf(gload(&scal[0]));
      float invbk = beta / fmaxf(sqrtf(nk2), 1e-12f);
      float esum = 0.f;
#pragma unroll 1
      for (int it = 0; it < 16; ++it){
        int ml = it * 8 + wv;
        float4 v  = *(const float4*)(&s_mem[ml * Dsz + ln * 4]);
        float4 kv = *(const float4*)(&s_a[ln * 4]);
        float d = wred64(v.x*kv.x + v.y*kv.y + v.z*kv.z + v.w*kv.w);
        float score = d * invbk / fmaxf(s_norm[ml], 1e-12f);
        float e = __expf(score - beta);
        if (ln == 0){ s_e[ml] = e; esum += e; }
      }
      if (ln == 0) s_wsum[wv] = esum;
      __syncthreads();
      if (tid == 0){
        float tot = 0.f;
#pragma unroll
        for (int k = 0; k < 8; ++k) tot += s_wsum[k];
        gstore(&psA[b], tot);
        gstore(&eF[b], s_e[0]);  gstore(&eL[b], s_e[RPB-1]);
        gstore(&pF[b], s_ww[0]); gstore(&pL[b], s_ww[RPB-1]);
      }
    }
    float S_w = gbar();   // carried: write-head softmax denom

    // ---- F: write-head interpolate + shift + sharpen ----
    shiftSharpen(0, s_ww, S_w);
    float Sw = gbar();    // carried: write-weight normalizer

    // ---- H: normalize ww, memory update, new norms + read scores ----
    {
      if (tid < 256){ s_a[tid] = gload(&ersv[tid]); s_b[tid] = gload(&addv[tid]); s_c[tid] = gload(&keyr[tid]); }
      float nk2 = bred512((tid < 256) ? s_c[tid] * s_c[tid] : 0.f);
      float beta  = softplusf(gload(&scal[6]));
      float invbk = beta / fmaxf(sqrtf(nk2), 1e-12f);
      float invSw = 1.f / (Sw + 1e-8f);
      if (tid < RPB) s_ww[tid] = s_bw[tid] * invSw;
      float esum = 0.f;
#pragma unroll 1
      for (int it = 0; it < 16; ++it){
        int ml = it * 8 + wv;
        float wwm = s_bw[ml] * invSw;
        int off = ml * Dsz + ln * 4;
        float4 mv = *(const float4*)(&s_mem[off]);
        float4 er = *(const float4*)(&s_a[ln * 4]);
        float4 ad = *(const float4*)(&s_b[ln * 4]);
        float4 kr = *(const float4*)(&s_c[ln * 4]);
        float4 nv;
        nv.x = mv.x * (1.f - wwm * er.x) + wwm * ad.x;
        nv.y = mv.y * (1.f - wwm * er.y) + wwm * ad.y;
        nv.z = mv.z * (1.f - wwm * er.z) + wwm * ad.z;
        nv.w = mv.w * (1.f - wwm * er.w) + wwm * ad.w;
        *(float4*)(&s_mem[off]) = nv;
        float n2 = nv.x*nv.x + nv.y*nv.y + nv.z*nv.z + nv.w*nv.w;
        float dt = nv.x*kr.x + nv.y*kr.y + nv.z*kr.z + nv.w*kr.w;
        n2 = wred64(n2);
        dt = wred64(dt);
        float nr = sqrtf(n2);
        if (ln == 0) s_norm[ml] = nr;
        float score = dt * invbk / fmaxf(nr, 1e-12f);
        float e = __expf(score - beta);
        if (ln == 0){ s_e[ml] = e; esum += e; }
      }
      if (ln == 0) s_wsum[wv] = esum;
      __syncthreads();
      if (tid == 0){
        float tot = 0.f;
#pragma unroll
        for (int k = 0; k < 8; ++k) tot += s_wsum[k];
        gstore(&psA[b], tot);
        gstore(&eF[b], s_e[0]);  gstore(&eL[b], s_e[RPB-1]);
        gstore(&pF[b], s_rw[0]); gstore(&pL[b], s_rw[RPB-1]);
      }
    }
    float S_r = gbar();   // carried: read-head softmax denom

    // ---- J: read-head shift+sharpen; UNNORMALIZED rvec partials ----
    {
      shiftSharpen(6, s_rw, S_r);
      __syncthreads();
      int col = tid & 255, half = tid >> 8;
      float acc = 0.f;
#pragma unroll 1
      for (int j = half * 64; j < half * 64 + 64; ++j) acc += s_bw[j] * s_mem[j * Dsz + col];
      if (half == 0) s_a[col] = acc;
      __syncthreads();
      if (half == 1) atomicAdd(&parts[(b & (NG-1)) * 256 + col], acc + s_a[col]);
    }
    Srcarry = gbar();     // carried: read-weight normalizer for A(t+1)
  }
}

extern "C" void kernel_launch(void* const* d_in, const int* in_sizes, int n_in,
                              void* d_out, int out_size, void* d_ws, size_t ws_size,
                              hipStream_t stream)
{
  (void)in_sizes; (void)out_size;
  if (n_in < 34) return;
  if (ws_size < (size_t)65536) return;   // ~46KB scratch needed
  Params P;
  for (int i = 0; i < 34; ++i) P.in[i] = (const float*)d_in[i];
  P.out = (float*)d_out;
  P.ws  = (float*)d_ws;
  hipLaunchKernelGGL(ntm_kernel, dim3(NBLK + 1), dim3(NTHR), 0, stream, P);
}